// Round 12
// baseline (91.988 us; speedup 1.0000x reference)
//
#include <hip/hip_runtime.h>

#define DIM_W 160
#define DIM_H 192
#define DIM_D 160
#define DIM_B 2

constexpr int TW = 16;      // output tile width
constexpr int TH = 24;      // output tile height (P=2 px/thread, 12 emit-lanes)
constexpr int CH = 19;      // depth outputs per chunk (27 slices = 3 x 9)
constexpr int NCH = 9;      // ceil(160/19)
constexpr int RH = 32;      // region rows (TH + 8)
constexpr int RWDS = 24;    // words per region row (4 + 16 + 4)
constexpr float INV_K = 1.0f / 729.0f;
constexpr double NTOT = 9830400.0;

typedef unsigned int u32;
typedef __attribute__((address_space(1))) const u32 gu32;
typedef __attribute__((address_space(3))) u32 lu32;

__global__ void init_kernel(float* out, float* ws) {
    out[0] = 0.0f;
    ws[0] = 0.0f; ws[1] = 0.0f; ws[2] = 0.0f; ws[3] = 0.0f;
}

__device__ __forceinline__ int clampD(int s) {
    return s < 0 ? 0 : (s > DIM_D - 1 ? DIM_D - 1 : s);
}

// DPP helper: returns v shuffled by ctrl within 16-lane rows, OOB -> 0
#define DPPF(v, ctrl) __builtin_bit_cast(float, \
    __builtin_amdgcn_update_dpp(0, __builtin_bit_cast(int, (float)(v)), \
                                (ctrl), 0xF, 0xF, true))

// 5-field pair-scan stage-2: r0v/r1v = per-row W-sums of rows 2i / 2i+1.
// S1/S2/S4/S8 must fetch lane i-1/i-2/i-4/i-8; SL4 must fetch lane i+4.
#define SCAN5(S1, S2, S4, S8, SL4) \
    _Pragma("unroll") \
    for (int f = 0; f < 5; ++f) { \
        float L = r0v[f] + r1v[f]; \
        L += DPPF(L, S1); L += DPPF(L, S2); \
        L += DPPF(L, S4); L += DPPF(L, S8); \
        const float Pp4 = DPPF(L, SL4); \
        const float Pm1 = DPPF(L, S1); \
        const float r9v = DPPF(r1v[f], SL4); \
        w0v[f] = Pp4 - r9v - Pm1; \
        w1v[f] = Pp4 - Pm1 - r0v[f]; \
    }

__global__ __launch_bounds__(256)
void lncc3d_kernel(const float* __restrict__ I,
                   const float* __restrict__ T,
                   const float* __restrict__ zsrc,
                   float* __restrict__ out)
{
    // slice region: [buf][field][768 words] = 32 rows x 24 words, glds-staged
    // (3 chunks x 64 lanes x 16B per field, exact cover). Stage-1 phase
    // (4r x 4g) hits quad (6r+g+c) mod 8 exactly twice -> conflict-free.
    __shared__ __align__(16) float sR[2][2][768];
    // per-row W-sums (I,T,II,TT): col rotated by R(r)=r+(r>>1):
    // writes (4g+q+R) 2-way; scan reads (wo+3i) mod 8 2-way.
    __shared__ __align__(16) float4 wA[RH][16];
    // per-row W-sums IT, transposed [w][row], stride 34
    __shared__ __align__(16) float  wB[16][34];
    __shared__ float red[4];

    const int tid  = threadIdx.x;
    const int lane = tid & 63;
    const int wid  = tid >> 6;
    const int wo   = tid >> 4;            // 0..15 (16-lane DPP row = one w)
    const int i    = tid & 15;            // scan lane within column

    const int bw = blockIdx.x, bh = blockIdx.y, bz = blockIdx.z;
    const int b  = bz / NCH;
    const int c  = bz - b * NCH;
    const int w0 = bw * TW, h0 = bh * TH, d0 = c * CH;
    const int dEnd = min(d0 + CH, DIM_D);

    const int plane = DIM_H * DIM_W;
    const float* Ib = I + (size_t)b * DIM_D * plane;
    const float* Tb = T + (size_t)b * DIM_D * plane;

    // DPP direction probe (validated in r9: passed refcheck)
    const int shp = __builtin_amdgcn_update_dpp(0, lane, 0x104, 0xF, 0xF, true);
    const bool dirA = (__builtin_amdgcn_readfirstlane(shp) == 4);

    // glds roles: waves 2,3 stage field I / T (3 chunks each)
    const bool ldw = (wid >= 2);
    const int  fldg = (wid == 3);
    const float* Fbg = fldg ? Tb : Ib;
    int goff[3];
#pragma unroll
    for (int kk = 0; kk < 3; ++kk) {
        const int s16 = kk * 64 + lane;
        const int row = s16 / 6;
        const int q   = s16 - row * 6;
        const int gh  = h0 - 4 + row;
        const int gw  = w0 - 4 + (q << 2);
        goff[kk] = (gh >= 0 && gh < DIM_H && gw >= 0 && gw <= DIM_W - 4)
                   ? (gh * DIM_W + gw) : -1;
    }

    auto issue = [&](int sc, int buf) {
        if (ldw) {
            const float* Fs = Fbg + (size_t)sc * plane;
#pragma unroll
            for (int kk = 0; kk < 3; ++kk) {
                const float* gp = (goff[kk] >= 0) ? (Fs + goff[kk]) : zsrc;
                __builtin_amdgcn_global_load_lds((gu32*)gp,
                    (lu32*)&sR[buf][fldg][kk << 8], 16, 0, 0);
            }
        }
    };

    // D-rings (slot = static j) + running sums: [px][field {I,T,II,TT,IT}]
    float rg[2][5][9], rn[2][5];
#pragma unroll
    for (int p = 0; p < 2; ++p) {
#pragma unroll
        for (int f = 0; f < 5; ++f) {
            rn[p][f] = 0.0f;
#pragma unroll
            for (int q = 0; q < 9; ++q) rg[p][f][q] = 0.0f;
        }
    }
    float acc = 0.0f;

    const int sStart = d0 - 4;
    int cur = 0;

    // ---- prologue ----
    issue(clampD(sStart), 0);
    issue(clampD(sStart + 1), 1);
    if (ldw) { asm volatile("s_waitcnt vmcnt(3)" ::: "memory"); }
    __builtin_amdgcn_s_barrier();

    for (int t = 0; t < 3; ++t) {
        const int t9 = t * 9;
#pragma unroll
        for (int j = 0; j < 9; ++j) {
            const int s  = sStart + t9 + j;
            const bool vs = (s >= 0) && (s < DIM_D);

            // ---- stage 1: 9-wide W sums, waves 0-1 (32 rows x 4 groups) ----
            if (vs && tid < 128) {
                const int r  = tid >> 2;       // 0..31
                const int g  = tid & 3;
                const int c0 = g << 2;
                const int rr = r + (r >> 1);
                const float* rIp = &sR[cur][0][r * RWDS];
                const float* rTp = &sR[cur][1][r * RWDS];
                const float4 ia  = *(const float4*)(rIp + c0);
                const float4 ib4 = *(const float4*)(rIp + c0 + 4);
                const float4 ic4 = *(const float4*)(rIp + c0 + 8);
                const float4 ta  = *(const float4*)(rTp + c0);
                const float4 tb4 = *(const float4*)(rTp + c0 + 4);
                const float4 tc4 = *(const float4*)(rTp + c0 + 8);
                const float iv[12] = {ia.x, ia.y, ia.z, ia.w, ib4.x, ib4.y, ib4.z, ib4.w,
                                      ic4.x, ic4.y, ic4.z, ic4.w};
                const float tv[12] = {ta.x, ta.y, ta.z, ta.w, tb4.x, tb4.y, tb4.z, tb4.w,
                                      tc4.x, tc4.y, tc4.z, tc4.w};
                float aI = 0.f, aT = 0.f, aII = 0.f, aTT = 0.f, aIT = 0.f;
#pragma unroll
                for (int k = 0; k < 9; ++k) {
                    aI += iv[k]; aT += tv[k];
                    aII = fmaf(iv[k], iv[k], aII);
                    aTT = fmaf(tv[k], tv[k], aTT);
                    aIT = fmaf(iv[k], tv[k], aIT);
                }
                wA[r][(c0 + rr) & 15] = make_float4(aI, aT, aII, aTT);
                wB[c0][r] = aIT;
#pragma unroll
                for (int q = 1; q < 4; ++q) {
                    const float ni = iv[8 + q], oi = iv[q - 1];
                    const float nt = tv[8 + q], ot = tv[q - 1];
                    aI += ni - oi; aT += nt - ot;
                    aII = fmaf(ni, ni, fmaf(oi, -oi, aII));
                    aTT = fmaf(nt, nt, fmaf(ot, -ot, aTT));
                    aIT = fmaf(ni, nt, fmaf(oi, -ot, aIT));
                    wA[r][(c0 + q + rr) & 15] = make_float4(aI, aT, aII, aTT);
                    wB[c0 + q][r] = aIT;
                }
            }
            asm volatile("s_waitcnt lgkmcnt(0)" ::: "memory");
            __builtin_amdgcn_s_barrier();   // wA/wB published; sR[cur] reads done

            // ---- issue glds for slice s+2 into sR[cur] ----
            issue(clampD(s + 2), cur);

            // ---- stage 2: per-column DPP scan -> window sums; rings; emit ----
            float w0v[5], w1v[5];
            if (vs) {
                float r0v[5], r1v[5];
                const float4 A0 = wA[2 * i][(wo + 3 * i) & 15];
                const float4 A1 = wA[2 * i + 1][(wo + 3 * i + 1) & 15];
                const float2 Bv = *(const float2*)&wB[wo][2 * i];
                r0v[0] = A0.x; r0v[1] = A0.y; r0v[2] = A0.z; r0v[3] = A0.w; r0v[4] = Bv.x;
                r1v[0] = A1.x; r1v[1] = A1.y; r1v[2] = A1.z; r1v[3] = A1.w; r1v[4] = Bv.y;
                if (dirA) {
                    SCAN5(0x111, 0x112, 0x114, 0x118, 0x104)
                } else {
                    SCAN5(0x101, 0x102, 0x104, 0x108, 0x114)
                }
            } else {
#pragma unroll
                for (int f = 0; f < 5; ++f) { w0v[f] = 0.f; w1v[f] = 0.f; }
            }

#pragma unroll
            for (int f = 0; f < 5; ++f) {
                rn[0][f] += w0v[f] - rg[0][f][j];  rg[0][f][j] = w0v[f];
                rn[1][f] += w1v[f] - rg[1][f][j];  rg[1][f][j] = w1v[f];
            }

            if ((s >= d0 + 4) && ((s - 4) < dEnd) && (i < 12)) {
#pragma unroll
                for (int p = 0; p < 2; ++p) {
                    const float cr  = rn[p][4] - rn[p][0] * rn[p][1] * INV_K;
                    const float vv  = rn[p][2] - rn[p][0] * rn[p][0] * INV_K;
                    const float tvv = rn[p][3] - rn[p][1] * rn[p][1] * INV_K;
                    acc += cr * cr * __builtin_amdgcn_rcpf(fmaf(tvv, vv, 1e-5f));
                }
            }

            // ---- certify glds for slice s+1 landed (s+2's stay in flight) ----
            asm volatile("s_waitcnt lgkmcnt(0)" ::: "memory");
            if (ldw) { asm volatile("s_waitcnt vmcnt(3)" ::: "memory"); }
            __builtin_amdgcn_s_barrier();
            cur ^= 1;
        }
    }

    // ---- block reduction ----
#pragma unroll
    for (int off = 32; off > 0; off >>= 1) acc += __shfl_down(acc, off, 64);
    if (lane == 0) red[wid] = acc;
    __syncthreads();
    if (tid == 0) {
        const float bs = red[0] + red[1] + red[2] + red[3];
        atomicAdd(out, bs * (float)(-1.0 / NTOT));
    }
}

extern "C" void kernel_launch(void* const* d_in, const int* in_sizes, int n_in,
                              void* d_out, int out_size, void* d_ws, size_t ws_size,
                              hipStream_t stream) {
    const float* I = (const float*)d_in[0];
    const float* T = (const float*)d_in[1];
    float* out = (float*)d_out;
    float* ws  = (float*)d_ws;

    init_kernel<<<dim3(1), dim3(1), 0, stream>>>(out, ws);

    dim3 grid(DIM_W / TW, DIM_H / TH, DIM_B * NCH); // 10 x 8 x 18 = 1440
    dim3 block(256);
    lncc3d_kernel<<<grid, block, 0, stream>>>(I, T, ws, out);
}

// Round 13
// 83.471 us; speedup vs baseline: 1.1020x; 1.1020x over previous
//
#include <hip/hip_runtime.h>

#define DIM_W 160
#define DIM_H 192
#define DIM_D 160
#define DIM_B 2

constexpr int TW = 16;      // output tile width
constexpr int TH = 32;      // output tile height (P=2 px/thread in H)
constexpr int CH = 19;      // depth outputs per chunk (27 slices = 3 x 9)
constexpr int NCH = 9;      // ceil(160/19)
constexpr int RH = TH + 8;  // 40 region rows
constexpr float INV_K = 1.0f / 729.0f;
constexpr double NTOT = 9830400.0;

typedef unsigned int u32;
typedef __attribute__((address_space(1))) const u32 gu32;
typedef __attribute__((address_space(3))) u32 lu32;
typedef _Float16 h2 __attribute__((ext_vector_type(2)));

__global__ void init_kernel(float* out, float* ws) {
    out[0] = 0.0f;
    ws[0] = 0.0f; ws[1] = 0.0f; ws[2] = 0.0f; ws[3] = 0.0f;
}

__device__ __forceinline__ int clampD(int s) {
    return s < 0 ? 0 : (s > DIM_D - 1 ? DIM_D - 1 : s);
}

__device__ __forceinline__ u32 pkf16(float a, float b) {
    return __builtin_bit_cast(u32, __builtin_amdgcn_cvt_pkrtz(a, b));
}

__global__ __launch_bounds__(256)
void lncc3d_kernel(const float* __restrict__ I,
                   const float* __restrict__ T,
                   const float* __restrict__ zsrc,
                   float* __restrict__ out)
{
    // slice region, glds-staged (as r10): [buf][field][row][32 words], row=128B,
    // logical f4 q of row r at physical (q + 2r) & 7 (source-side rotation).
    __shared__ __align__(16) float sR[2][2][RH][32];
    // W-sums packed f16: cell = {pk(I,T), pk(II,TT)} = 8B; col rotated (c+row)&15.
    // Row = 128B -> b64 reads hit each bank exactly 4x (minimum) = conflict-free.
    __shared__ __align__(16) uint2 wA[RH][16];
    // W-sums IT, f32, transposed [w][row], stride 44 (as r10)
    __shared__ __align__(16) float  wB[16][44];
    __shared__ float red[4];

    const int tid  = threadIdx.x;
    const int lane = tid & 63;
    const int wid  = tid >> 6;
    const int wo   = tid & 15;
    const int hb   = (tid >> 4) << 1;

    const int bw = blockIdx.x, bh = blockIdx.y, bz = blockIdx.z;
    const int b  = bz / NCH;
    const int c  = bz - b * NCH;
    const int w0 = bw * TW, h0 = bh * TH, d0 = c * CH;
    const int dEnd = min(d0 + CH, DIM_D);

    const int plane = DIM_H * DIM_W;
    const int fld  = wid >> 1;            // 0: field I, 1: field T
    const int kodd = wid & 1;             // chunk set {1,3} vs {0,2,4}
    const int nck  = kodd ? 2 : 3;        // glds per wave per slice
    const float* Fb = (fld ? T : I) + (size_t)b * DIM_D * plane;

    // per-lane glds source offsets (2r rotation folded into source address)
    int boff[3], crw[3];
#pragma unroll
    for (int i = 0; i < 3; ++i) {
        const int ck  = kodd ? (2 * i + 1) : (2 * i);
        const int row = 8 * ck + (lane >> 3);
        const int pf4 = lane & 7;
        const int lf4 = (pf4 - 2 * row) & 7;
        const int gh  = h0 - 4 + row;
        const int gw  = w0 - 8 + (lf4 << 2);
        crw[i]  = 8 * ck;
        boff[i] = (i < nck && gh >= 0 && gh < DIM_H && gw >= 0 && gw <= DIM_W - 4)
                  ? (gh * DIM_W + gw) : -1;
    }

    auto issue = [&](int sc, int buf) {
        const float* Fs = Fb + (size_t)sc * plane;
#pragma unroll
        for (int i = 0; i < 3; ++i) {
            if (i < nck) {
                const float* gp = (boff[i] >= 0) ? (Fs + boff[i]) : zsrc;
                __builtin_amdgcn_global_load_lds((gu32*)gp, (lu32*)&sR[buf][fld][crw[i]][0],
                                                 16, 0, 0);
            }
        }
    };

    // D-rings (slot = static J) + running sums, 5 fields x 2 px (f32)
    float rgI[2][9], rgT[2][9], rgII[2][9], rgTT[2][9], rgIT[2][9];
    float rnI[2], rnT[2], rnII[2], rnTT[2], rnIT[2];
#pragma unroll
    for (int p = 0; p < 2; ++p) {
        rnI[p] = rnT[p] = rnII[p] = rnTT[p] = rnIT[p] = 0.0f;
#pragma unroll
        for (int q = 0; q < 9; ++q) {
            rgI[p][q] = rgT[p][q] = rgII[p][q] = rgTT[p][q] = rgIT[p][q] = 0.0f;
        }
    }
    float acc = 0.0f;

    const int sStart = d0 - 4;
    int cur = 0;

    // ---- prologue: stage sStart -> buf0, sStart+1 -> buf1 ----
    issue(clampD(sStart), 0);
    issue(clampD(sStart + 1), 1);
    if (kodd) { asm volatile("s_waitcnt vmcnt(2)" ::: "memory"); }
    else      { asm volatile("s_waitcnt vmcnt(3)" ::: "memory"); }
    __builtin_amdgcn_s_barrier();

    for (int t = 0; t < 3; ++t) {
        const int t9 = t * 9;
#pragma unroll
        for (int j = 0; j < 9; ++j) {
            const int s  = sStart + t9 + j;
            const bool vs = (s >= 0) && (s < DIM_D);

            // ---- stage 1: 9-wide W sums on sR[cur] ----
            if (vs && tid < 160) {
                const int r = tid >> 2;
                const int g = tid & 3;
                const float* rIp = &sR[cur][0][r][0];
                const float* rTp = &sR[cur][1][r][0];
                const int q0 = ((g + 1 + 2 * r) & 7) << 2;
                const int q1 = ((g + 2 + 2 * r) & 7) << 2;
                const int q2 = ((g + 3 + 2 * r) & 7) << 2;
                const float4 ia  = *(const float4*)(rIp + q0);
                const float4 ib4 = *(const float4*)(rIp + q1);
                const float4 ic4 = *(const float4*)(rIp + q2);
                const float4 ta  = *(const float4*)(rTp + q0);
                const float4 tb4 = *(const float4*)(rTp + q1);
                const float4 tc4 = *(const float4*)(rTp + q2);
                const float iv[12] = {ia.x, ia.y, ia.z, ia.w, ib4.x, ib4.y, ib4.z, ib4.w,
                                      ic4.x, ic4.y, ic4.z, ic4.w};
                const float tv[12] = {ta.x, ta.y, ta.z, ta.w, tb4.x, tb4.y, tb4.z, tb4.w,
                                      tc4.x, tc4.y, tc4.z, tc4.w};
                float aI = 0.f, aT = 0.f, aII = 0.f, aTT = 0.f, aIT = 0.f;
#pragma unroll
                for (int k = 0; k < 9; ++k) {
                    aI += iv[k]; aT += tv[k];
                    aII = fmaf(iv[k], iv[k], aII);
                    aTT = fmaf(tv[k], tv[k], aTT);
                    aIT = fmaf(iv[k], tv[k], aIT);
                }
                const int c0 = g << 2;
                wA[r][(c0 + r) & 15] = make_uint2(pkf16(aI, aT), pkf16(aII, aTT));
                wB[c0][r] = aIT;
#pragma unroll
                for (int q = 1; q < 4; ++q) {
                    const float ni = iv[8 + q], oi = iv[q - 1];
                    const float nt = tv[8 + q], ot = tv[q - 1];
                    aI += ni - oi; aT += nt - ot;
                    aII = fmaf(ni, ni, fmaf(oi, -oi, aII));
                    aTT = fmaf(nt, nt, fmaf(ot, -ot, aTT));
                    aIT = fmaf(ni, nt, fmaf(oi, -ot, aIT));
                    wA[r][(c0 + q + r) & 15] = make_uint2(pkf16(aI, aT), pkf16(aII, aTT));
                    wB[c0 + q][r] = aIT;
                }
            }
            asm volatile("s_waitcnt lgkmcnt(0)" ::: "memory");
            __builtin_amdgcn_s_barrier();   // wA/wB published; sR[cur] reads done

            // ---- issue glds for slice s+2 into sR[cur] (safe: readers done) ----
            issue(clampD(s + 2), cur);

            // ---- stage 2: 9-tall H sums (2 px) with packed f16 adds ----
            float s2I0, s2T0, s2II0, s2TT0, s2IT0, s2I1, s2T1, s2II1, s2TT1, s2IT1;
            if (vs) {
                const uint2 C0 = wA[hb][(wo + hb) & 15];
                const h2 A0a = __builtin_bit_cast(h2, C0.x);
                const h2 A0b = __builtin_bit_cast(h2, C0.y);
                h2 SA = A0a, SB = A0b;
#pragma unroll
                for (int k = 1; k < 9; ++k) {
                    const uint2 Ck = wA[hb + k][(wo + hb + k) & 15];
                    SA += __builtin_bit_cast(h2, Ck.x);
                    SB += __builtin_bit_cast(h2, Ck.y);
                }
                const uint2 C9 = wA[hb + 9][(wo + hb + 9) & 15];
                const h2 P1A = SA - A0a + __builtin_bit_cast(h2, C9.x);
                const h2 P1B = SB - A0b + __builtin_bit_cast(h2, C9.y);
                s2I0  = (float)SA.x;  s2T0  = (float)SA.y;
                s2II0 = (float)SB.x;  s2TT0 = (float)SB.y;
                s2I1  = (float)P1A.x; s2T1  = (float)P1A.y;
                s2II1 = (float)P1B.x; s2TT1 = (float)P1B.y;
                const float2 B0 = *(const float2*)&wB[wo][hb];
                const float2 B1 = *(const float2*)&wB[wo][hb + 2];
                const float2 B2 = *(const float2*)&wB[wo][hb + 4];
                const float2 B3 = *(const float2*)&wB[wo][hb + 6];
                const float2 B4 = *(const float2*)&wB[wo][hb + 8];
                s2IT0 = B0.x + B0.y + B1.x + B1.y + B2.x + B2.y
                      + B3.x + B3.y + B4.x;
                s2IT1 = s2IT0 - B0.x + B4.y;
            } else {
                s2I0 = s2T0 = s2II0 = s2TT0 = s2IT0 = 0.f;
                s2I1 = s2T1 = s2II1 = s2TT1 = s2IT1 = 0.f;
            }

            rnI[0]  += s2I0  - rgI[0][j];  rgI[0][j]  = s2I0;
            rnT[0]  += s2T0  - rgT[0][j];  rgT[0][j]  = s2T0;
            rnII[0] += s2II0 - rgII[0][j]; rgII[0][j] = s2II0;
            rnTT[0] += s2TT0 - rgTT[0][j]; rgTT[0][j] = s2TT0;
            rnIT[0] += s2IT0 - rgIT[0][j]; rgIT[0][j] = s2IT0;
            rnI[1]  += s2I1  - rgI[1][j];  rgI[1][j]  = s2I1;
            rnT[1]  += s2T1  - rgT[1][j];  rgT[1][j]  = s2T1;
            rnII[1] += s2II1 - rgII[1][j]; rgII[1][j] = s2II1;
            rnTT[1] += s2TT1 - rgTT[1][j]; rgTT[1][j] = s2TT1;
            rnIT[1] += s2IT1 - rgIT[1][j]; rgIT[1][j] = s2IT1;

            if ((s >= d0 + 4) && ((s - 4) < dEnd)) {
                float cr, vv, tvv;
                cr  = rnIT[0] - rnI[0] * rnT[0] * INV_K;
                vv  = rnII[0] - rnI[0] * rnI[0] * INV_K;
                tvv = rnTT[0] - rnT[0] * rnT[0] * INV_K;
                acc += cr * cr * __builtin_amdgcn_rcpf(fmaf(tvv, vv, 1e-5f));
                cr  = rnIT[1] - rnI[1] * rnT[1] * INV_K;
                vv  = rnII[1] - rnI[1] * rnI[1] * INV_K;
                tvv = rnTT[1] - rnT[1] * rnT[1] * INV_K;
                acc += cr * cr * __builtin_amdgcn_rcpf(fmaf(tvv, vv, 1e-5f));
            }

            // ---- certify own glds for slice s+1 landed (s+2's stay in flight) ----
            asm volatile("s_waitcnt lgkmcnt(0)" ::: "memory");
            if (kodd) { asm volatile("s_waitcnt vmcnt(2)" ::: "memory"); }
            else      { asm volatile("s_waitcnt vmcnt(3)" ::: "memory"); }
            __builtin_amdgcn_s_barrier();
            cur ^= 1;
        }
    }

    // ---- block reduction ----
#pragma unroll
    for (int off = 32; off > 0; off >>= 1) acc += __shfl_down(acc, off, 64);
    if (lane == 0) red[wid] = acc;
    __syncthreads();
    if (tid == 0) {
        const float bs = red[0] + red[1] + red[2] + red[3];
        atomicAdd(out, bs * (float)(-1.0 / NTOT));
    }
}

extern "C" void kernel_launch(void* const* d_in, const int* in_sizes, int n_in,
                              void* d_out, int out_size, void* d_ws, size_t ws_size,
                              hipStream_t stream) {
    const float* I = (const float*)d_in[0];
    const float* T = (const float*)d_in[1];
    float* out = (float*)d_out;
    float* ws  = (float*)d_ws;

    init_kernel<<<dim3(1), dim3(1), 0, stream>>>(out, ws);

    dim3 grid(DIM_W / TW, DIM_H / TH, DIM_B * NCH); // 10 x 6 x 18 = 1080
    dim3 block(256);
    lncc3d_kernel<<<grid, block, 0, stream>>>(I, T, ws, out);
}